// Round 1
// baseline (178.051 us; speedup 1.0000x reference)
//
#include <hip/hip_runtime.h>
#include <stdint.h>

// KAN layer as bf16 MFMA GEMM: out = phi @ W^T + bias
//   phi[b, i*8+g] = normalized cubic-bump basis (g<5; 3 zero-pad columns)
//   W  [o, i*8+g] = coef[o,i,g]*scale[o,i] (bf16, precomputed into d_ws)
// Shapes: M=32768 (b), N=256 (o), K=2048 (padded from 1280).

#define B_SZ   32768
#define IN_SZ  256
#define OUT_SZ 256
#define KPAD   2048        // IN_SZ * 8 (G padded 5 -> 8)
#define EPSF   1e-8f

typedef __bf16 bf16x8 __attribute__((ext_vector_type(8)));
typedef unsigned short ushort8 __attribute__((ext_vector_type(8)));
typedef float floatx4 __attribute__((ext_vector_type(4)));

// float -> bf16 bits, round-nearest-even (manual: avoids __bf16 arithmetic deps)
__device__ __forceinline__ unsigned short f2bf(float f) {
  unsigned u = __float_as_uint(f);
  u += 0x7FFFu + ((u >> 16) & 1u);
  return (unsigned short)(u >> 16);
}

// monotone float<->uint encoding for atomic min/max
__device__ __forceinline__ unsigned enc_f32(float f) {
  unsigned u = __float_as_uint(f);
  return (u & 0x80000000u) ? ~u : (u | 0x80000000u);
}
__device__ __forceinline__ float dec_f32(unsigned e) {
  unsigned u = (e & 0x80000000u) ? (e ^ 0x80000000u) : ~e;
  return __uint_as_float(u);
}

__global__ void init_mm(unsigned* mm) {
  if (threadIdx.x == 0) { mm[0] = 0xFFFFFFFFu; mm[1] = 0u; }
}

__global__ void __launch_bounds__(256) minmax_kernel(const float* __restrict__ x,
                                                     unsigned* __restrict__ mm, int n4) {
  __shared__ unsigned smin, smax;
  if (threadIdx.x == 0) { smin = 0xFFFFFFFFu; smax = 0u; }
  __syncthreads();
  const float4* x4 = (const float4*)x;
  float lmin = 1e30f, lmax = -1e30f;
  for (int i = blockIdx.x * blockDim.x + threadIdx.x; i < n4; i += gridDim.x * blockDim.x) {
    float4 v = x4[i];
    lmin = fminf(lmin, fminf(fminf(v.x, v.y), fminf(v.z, v.w)));
    lmax = fmaxf(lmax, fmaxf(fmaxf(v.x, v.y), fmaxf(v.z, v.w)));
  }
  #pragma unroll
  for (int off = 32; off >= 1; off >>= 1) {
    lmin = fminf(lmin, __shfl_down(lmin, off, 64));
    lmax = fmaxf(lmax, __shfl_down(lmax, off, 64));
  }
  if ((threadIdx.x & 63) == 0) {
    atomicMin(&smin, enc_f32(lmin));
    atomicMax(&smax, enc_f32(lmax));
  }
  __syncthreads();
  if (threadIdx.x == 0) {
    atomicMin(&mm[0], smin);
    atomicMax(&mm[1], smax);
  }
}

// W[o][i*8+g] = coef[o][i][g] * scale[o][i], g<5; zeros for g>=5. bf16 bits.
__global__ void __launch_bounds__(256) wprep_kernel(const float* __restrict__ coef,
                                                    const float* __restrict__ scale,
                                                    unsigned short* __restrict__ w) {
  int idx = blockIdx.x * 256 + threadIdx.x;   // o*256 + i
  float s = scale[idx];
  const float* c = coef + idx * 5;
  ushort8 v;
  v[0] = f2bf(c[0] * s); v[1] = f2bf(c[1] * s); v[2] = f2bf(c[2] * s);
  v[3] = f2bf(c[3] * s); v[4] = f2bf(c[4] * s);
  v[5] = 0; v[6] = 0; v[7] = 0;
  *(ushort8*)(w + idx * 8) = v;   // 16B coalesced store
}

// ---- main fused GEMM ----
// block tile 128(b) x 128(o); 4 waves 2x2, each wave 4x4 MFMA 16x16 tiles.
// K loop: 64 iters of BK=32 (4 i's x 8 g). B staged via global_load_lds (unpadded,
// lane-linear — required). A (basis) computed in VALU, written to stride-40-padded LDS.
#define A_STRIDE 40

__global__ void __launch_bounds__(256, 2) kan_gemm(
    const float* __restrict__ x,            // [32768][256]
    const unsigned short* __restrict__ w,   // [256][2048] bf16 bits
    const float* __restrict__ bias,         // [256]
    const unsigned* __restrict__ mm,
    float* __restrict__ out)                // [32768][256]
{
  __shared__ __align__(16) unsigned short Ab[128 * A_STRIDE]; // 10 KB
  __shared__ __align__(16) unsigned short Bb[128 * 32];       // 8 KB

  const int t = threadIdx.x;
  const int lane = t & 63;
  const int wv = t >> 6;
  const int wm = wv & 1, wn = wv >> 1;
  const int l15 = lane & 15, lq = lane >> 4;
  const int bRow = blockIdx.x * 128;
  const int bCol = blockIdx.y * 128;

  const float xmin = dec_f32(mm[0]);
  const float xmax = dec_f32(mm[1]);
  const float sc = 2.0f / (xmax - xmin + EPSF);

  floatx4 acc[4][4] = {};

  // basis thread mapping: thread -> (row ab, ii pair). 512 values/iter, 2/thread.
  const int ab = t >> 1;              // 0..127
  const int aii = (t & 1) * 2;        // 0 or 2
  const float* xrow = x + (size_t)(bRow + ab) * IN_SZ;

  for (int ic = 0; ic < 8; ++ic) {    // i-chunks of 32
    // register-stage x for this chunk: 8 float2 (cols kk*4+aii, kk*4+aii+1)
    float2 xv[8];
    #pragma unroll
    for (int kk = 0; kk < 8; ++kk)
      xv[kk] = *(const float2*)(xrow + ic * 32 + kk * 4 + aii);

    #pragma unroll
    for (int kk = 0; kk < 8; ++kk) {
      const int kt = ic * 8 + kk;     // global k-iter, k = kt*32

      // stage B tile [128 o][32 k] bf16 via async global->LDS, 16B/lane
      #pragma unroll
      for (int r = 0; r < 2; ++r) {
        int seg = r * 256 + t;                  // 512 x 16B segments
        int orow = seg >> 2, c4 = seg & 3;
        const unsigned short* g = w + (size_t)(bCol + orow) * KPAD + kt * 32 + c4 * 8;
        __builtin_amdgcn_global_load_lds(
            (const __attribute__((address_space(1))) unsigned int*)g,
            (__attribute__((address_space(3))) unsigned int*)(Bb + seg * 8),
            16, 0, 0);
      }

      // compute basis for 2 x-values -> two 16B A-tile segments
      #pragma unroll
      for (int j = 0; j < 2; ++j) {
        float xnv = ((j ? xv[kk].y : xv[kk].x) - xmin) * sc - 1.0f;
        float d0 = fabsf(xnv + 1.0f);
        float d1 = fabsf(xnv + 0.5f);
        float d2 = fabsf(xnv);
        float d3 = fabsf(xnv - 0.5f);
        float d4 = fabsf(xnv - 1.0f);
        float b0 = d0 < 1.0f ? 1.0f - d0 * d0 * d0 : 0.0f;
        float b1 = d1 < 1.0f ? 1.0f - d1 * d1 * d1 : 0.0f;
        float b2 = d2 < 1.0f ? 1.0f - d2 * d2 * d2 : 0.0f;
        float b3 = d3 < 1.0f ? 1.0f - d3 * d3 * d3 : 0.0f;
        float b4 = d4 < 1.0f ? 1.0f - d4 * d4 * d4 : 0.0f;
        float sum = b0 + b1 + b2 + b3 + b4 + EPSF;
        float inv = __builtin_amdgcn_rcpf(sum);
        ushort8 av;
        av[0] = f2bf(b0 * inv); av[1] = f2bf(b1 * inv); av[2] = f2bf(b2 * inv);
        av[3] = f2bf(b3 * inv); av[4] = f2bf(b4 * inv);
        av[5] = 0; av[6] = 0; av[7] = 0;
        *(ushort8*)(Ab + ab * A_STRIDE + (aii + j) * 8) = av;
      }

      __syncthreads();  // drains global_load_lds (vmcnt) + A ds_writes

      bf16x8 af[4], bfr[4];
      #pragma unroll
      for (int mi = 0; mi < 4; ++mi)
        af[mi] = *(const bf16x8*)(Ab + (wm * 64 + mi * 16 + l15) * A_STRIDE + lq * 8);
      #pragma unroll
      for (int ni = 0; ni < 4; ++ni)
        bfr[ni] = *(const bf16x8*)(Bb + (wn * 64 + ni * 16 + l15) * 32 + lq * 8);

      #pragma unroll
      for (int mi = 0; mi < 4; ++mi)
        #pragma unroll
        for (int ni = 0; ni < 4; ++ni)
          acc[mi][ni] = __builtin_amdgcn_mfma_f32_16x16x32_bf16(af[mi], bfr[ni], acc[mi][ni], 0, 0, 0);

      __syncthreads();  // protect A/B LDS before next iter's staging
    }
  }

  // epilogue: C/D layout col=lane&15, row=(lane>>4)*4+reg  [verified m89/m91]
  #pragma unroll
  for (int ni = 0; ni < 4; ++ni) {
    int o = bCol + wn * 64 + ni * 16 + l15;
    float bs = bias[o];
    #pragma unroll
    for (int mi = 0; mi < 4; ++mi) {
      int rbase = bRow + wm * 64 + mi * 16 + lq * 4;
      #pragma unroll
      for (int r = 0; r < 4; ++r)
        out[(size_t)(rbase + r) * OUT_SZ + o] = acc[mi][ni][r] + bs;
    }
  }
}

extern "C" void kernel_launch(void* const* d_in, const int* in_sizes, int n_in,
                              void* d_out, int out_size, void* d_ws, size_t ws_size,
                              hipStream_t stream) {
  const float* x     = (const float*)d_in[0];
  // d_in[1] = grid: known linspace(-1,1,5), hardcoded in basis math
  const float* coef  = (const float*)d_in[2];
  const float* scale = (const float*)d_in[3];
  const float* bias  = (const float*)d_in[4];
  float* out = (float*)d_out;

  // workspace layout: [0..7] minmax uints, [16..] W bf16 [256][2048] = 1 MB
  size_t need = 16 + (size_t)OUT_SZ * KPAD * 2;
  if (ws_size < need) return;  // fails loud (poisoned out) rather than corrupting

  unsigned* mm = (unsigned*)d_ws;
  unsigned short* w = (unsigned short*)((char*)d_ws + 16);

  init_mm<<<1, 64, 0, stream>>>(mm);
  minmax_kernel<<<1024, 256, 0, stream>>>(x, mm, (B_SZ * IN_SZ) / 4);
  wprep_kernel<<<(OUT_SZ * IN_SZ) / 256, 256, 0, stream>>>(coef, scale, w);
  dim3 g(B_SZ / 128, OUT_SZ / 128);
  kan_gemm<<<g, 256, 0, stream>>>(x, w, bias, mm, out);
}

// Round 2
// 164.120 us; speedup vs baseline: 1.0849x; 1.0849x over previous
//
#include <hip/hip_runtime.h>
#include <stdint.h>

// KAN layer as bf16 MFMA GEMM: out = phi @ W^T + bias
//   phi[b, i*8+g] = normalized cubic-bump basis (g<5; 3 zero-pad cols)
//   W  [o, i*8+g] = coef[o,i,g]*scale[o,i] (bf16, in d_ws)
// M=32768, N=256, K=2048 (padded from 1280).
// R2: double-buffered LDS (1 barrier/iter, staging issued post-barrier),
//     XOR-swizzled B tile (kills 8-way ds_read conflicts),
//     32x32x16 MFMA (half LDS frag traffic per FLOP vs 16x16x32).

#define B_SZ   32768
#define IN_SZ  256
#define OUT_SZ 256
#define KPAD   2048
#define EPSF   1e-8f

#define A_STRIDE 40          // ushorts; 80 B rows -> conflict-free b128 reads
#define AB_BUF   (128 * A_STRIDE)   // 5120 ushorts per buffer
#define BB_BUF   (128 * 32)         // 4096 ushorts per buffer

typedef __bf16 bf16x8 __attribute__((ext_vector_type(8)));
typedef unsigned short ushort8 __attribute__((ext_vector_type(8)));
typedef float floatx16 __attribute__((ext_vector_type(16)));

__device__ __forceinline__ unsigned short f2bf(float f) {
  unsigned u = __float_as_uint(f);
  u += 0x7FFFu + ((u >> 16) & 1u);
  return (unsigned short)(u >> 16);
}
__device__ __forceinline__ unsigned enc_f32(float f) {
  unsigned u = __float_as_uint(f);
  return (u & 0x80000000u) ? ~u : (u | 0x80000000u);
}
__device__ __forceinline__ float dec_f32(unsigned e) {
  unsigned u = (e & 0x80000000u) ? (e ^ 0x80000000u) : ~e;
  return __uint_as_float(u);
}

// W pack + minmax init in one kernel (one fewer launch)
__global__ void __launch_bounds__(256) wprep_init(const float* __restrict__ coef,
                                                  const float* __restrict__ scale,
                                                  unsigned short* __restrict__ w,
                                                  unsigned* __restrict__ mm) {
  if (blockIdx.x == 0 && threadIdx.x == 0) { mm[0] = 0xFFFFFFFFu; mm[1] = 0u; }
  int idx = blockIdx.x * 256 + threadIdx.x;   // o*256 + i
  float s = scale[idx];
  const float* c = coef + idx * 5;
  ushort8 v;
  v[0] = f2bf(c[0] * s); v[1] = f2bf(c[1] * s); v[2] = f2bf(c[2] * s);
  v[3] = f2bf(c[3] * s); v[4] = f2bf(c[4] * s);
  v[5] = 0; v[6] = 0; v[7] = 0;
  *(ushort8*)(w + idx * 8) = v;
}

__global__ void __launch_bounds__(256) minmax_kernel(const float* __restrict__ x,
                                                     unsigned* __restrict__ mm, int n4) {
  __shared__ unsigned smin, smax;
  if (threadIdx.x == 0) { smin = 0xFFFFFFFFu; smax = 0u; }
  __syncthreads();
  const float4* x4 = (const float4*)x;
  float lmin = 1e30f, lmax = -1e30f;
  for (int i = blockIdx.x * blockDim.x + threadIdx.x; i < n4; i += gridDim.x * blockDim.x) {
    float4 v = x4[i];
    lmin = fminf(lmin, fminf(fminf(v.x, v.y), fminf(v.z, v.w)));
    lmax = fmaxf(lmax, fmaxf(fmaxf(v.x, v.y), fmaxf(v.z, v.w)));
  }
  #pragma unroll
  for (int off = 32; off >= 1; off >>= 1) {
    lmin = fminf(lmin, __shfl_down(lmin, off, 64));
    lmax = fmaxf(lmax, __shfl_down(lmax, off, 64));
  }
  if ((threadIdx.x & 63) == 0) {
    atomicMin(&smin, enc_f32(lmin));
    atomicMax(&smax, enc_f32(lmax));
  }
  __syncthreads();
  if (threadIdx.x == 0) {
    atomicMin(&mm[0], smin);
    atomicMax(&mm[1], smax);
  }
}

__global__ void __launch_bounds__(256, 2) kan_gemm(
    const float* __restrict__ x,            // [32768][256]
    const unsigned short* __restrict__ w,   // [256][2048] bf16 bits
    const float* __restrict__ bias,         // [256]
    const unsigned* __restrict__ mm,
    float* __restrict__ out)                // [32768][256]
{
  __shared__ __align__(16) unsigned short Ab[2 * AB_BUF]; // 20 KB (stride-40 pad)
  __shared__ __align__(16) unsigned short Bb[2 * BB_BUF]; // 16 KB (xor-swizzled)

  const int t = threadIdx.x;
  const int lane = t & 63;
  const int wv = t >> 6;
  const int wm = wv & 1, wn = wv >> 1;       // 2x2 wave grid, 64x64 wave tiles
  const int l31 = lane & 31, lh = lane >> 5; // 32x32 MFMA lane split
  const int bRow = blockIdx.x * 128;
  const int bCol = blockIdx.y * 128;

  const float xmin = dec_f32(mm[0]);
  const float xmax = dec_f32(mm[1]);
  const float sc = 2.0f / (xmax - xmin + EPSF);

  // basis mapping: thread -> (row ab, col pair aii)
  const int ab = t >> 1;
  const int aii = (t & 1) * 2;
  const float* xrow = x + (size_t)(bRow + ab) * IN_SZ;

  // B stage: 512 x 16B segs, xor-swizzled slot s=(c4+(o>>1))&3; LDS lane-linear.
  auto stageB = [&](int kt, int buf) {
    #pragma unroll
    for (int r = 0; r < 2; ++r) {
      int S = r * 256 + t;
      int o = S >> 2, s = S & 3;
      int c4 = (s - (o >> 1)) & 3;
      const unsigned short* g = w + (size_t)(bCol + o) * KPAD + kt * 32 + c4 * 8;
      __builtin_amdgcn_global_load_lds(
          (const __attribute__((address_space(1))) unsigned int*)g,
          (__attribute__((address_space(3))) unsigned int*)(Bb + buf * BB_BUF + S * 8),
          16, 0, 0);
    }
  };

  auto basis = [&](float2 xp, int buf) {
    #pragma unroll
    for (int j = 0; j < 2; ++j) {
      float xnv = ((j ? xp.y : xp.x) - xmin) * sc - 1.0f;
      float d0 = fabsf(xnv + 1.0f);
      float d1 = fabsf(xnv + 0.5f);
      float d2 = fabsf(xnv);
      float d3 = fabsf(xnv - 0.5f);
      float d4 = fabsf(xnv - 1.0f);
      float b0 = d0 < 1.0f ? 1.0f - d0 * d0 * d0 : 0.0f;
      float b1 = d1 < 1.0f ? 1.0f - d1 * d1 * d1 : 0.0f;
      float b2 = d2 < 1.0f ? 1.0f - d2 * d2 * d2 : 0.0f;
      float b3 = d3 < 1.0f ? 1.0f - d3 * d3 * d3 : 0.0f;
      float b4 = d4 < 1.0f ? 1.0f - d4 * d4 * d4 : 0.0f;
      float sum = b0 + b1 + b2 + b3 + b4 + EPSF;
      float inv = __builtin_amdgcn_rcpf(sum);
      ushort8 av;
      av[0] = f2bf(b0 * inv); av[1] = f2bf(b1 * inv); av[2] = f2bf(b2 * inv);
      av[3] = f2bf(b3 * inv); av[4] = f2bf(b4 * inv);
      av[5] = 0; av[6] = 0; av[7] = 0;
      *(ushort8*)(Ab + buf * AB_BUF + ab * A_STRIDE + (aii + j) * 8) = av;
    }
  };

  float2 xvc[8], xvn[8];
  auto loadx = [&](float2* xv, int ic) {
    #pragma unroll
    for (int kk = 0; kk < 8; ++kk)
      xv[kk] = *(const float2*)(xrow + ic * 32 + kk * 4 + aii);
  };

  floatx16 acc[2][2] = {};

  // prologue: stage iter 0 into buffer 0
  stageB(0, 0);
  loadx(xvc, 0);
  basis(xvc[0], 0);

  for (int ic = 0; ic < 8; ++ic) {
    #pragma unroll
    for (int kk = 0; kk < 8; ++kk) {
      const int kt = ic * 8 + kk;
      const int cur = kk & 1;        // ic*8 even -> compile-time buffer select
      const int nxt = cur ^ 1;

      __syncthreads();               // drains stage(kt): vmcnt + basis ds_writes

      if (kt < 63) {                 // prefetch kt+1 (overlaps with compute below)
        stageB(kt + 1, nxt);
        if (kk == 1 && ic < 7) loadx(xvn, ic + 1);
        float2 xp = (kk == 7) ? xvn[0] : xvc[kk + 1];
        basis(xp, nxt);
      }

      // compute iter kt from buffer cur: 2 k-steps of 32x32x16
      #pragma unroll
      for (int ks = 0; ks < 2; ++ks) {
        bf16x8 af[2], bfr[2];
        #pragma unroll
        for (int mi = 0; mi < 2; ++mi)
          af[mi] = *(const bf16x8*)(Ab + cur * AB_BUF +
                    (wm * 64 + mi * 32 + l31) * A_STRIDE + (ks * 2 + lh) * 8);
        #pragma unroll
        for (int ni = 0; ni < 2; ++ni) {
          int o = wn * 64 + ni * 32 + l31;
          int s = ((ks * 2 + lh) + (o >> 1)) & 3;      // xor-swizzle slot
          bfr[ni] = *(const bf16x8*)(Bb + cur * BB_BUF + o * 32 + s * 8);
        }
        #pragma unroll
        for (int mi = 0; mi < 2; ++mi)
          #pragma unroll
          for (int ni = 0; ni < 2; ++ni)
            acc[mi][ni] = __builtin_amdgcn_mfma_f32_32x32x16_bf16(
                af[mi], bfr[ni], acc[mi][ni], 0, 0, 0);
      }
    }
    if (ic < 7) {
      #pragma unroll
      for (int kk = 0; kk < 8; ++kk) xvc[kk] = xvn[kk];
    }
  }

  // epilogue: 32x32 C/D layout col=lane&31, row=(reg&3)+8*(reg>>2)+4*(lane>>5)
  #pragma unroll
  for (int ni = 0; ni < 2; ++ni) {
    int o = bCol + wn * 64 + ni * 32 + l31;
    float bs = bias[o];
    #pragma unroll
    for (int mi = 0; mi < 2; ++mi) {
      int rb = bRow + wm * 64 + mi * 32 + 4 * lh;
      #pragma unroll
      for (int reg = 0; reg < 16; ++reg) {
        int row = rb + (reg & 3) + 8 * (reg >> 2);
        out[(size_t)row * OUT_SZ + o] = acc[mi][ni][reg] + bs;
      }
    }
  }
}

extern "C" void kernel_launch(void* const* d_in, const int* in_sizes, int n_in,
                              void* d_out, int out_size, void* d_ws, size_t ws_size,
                              hipStream_t stream) {
  const float* x     = (const float*)d_in[0];
  // d_in[1] = grid: linspace(-1,1,5), hardcoded
  const float* coef  = (const float*)d_in[2];
  const float* scale = (const float*)d_in[3];
  const float* bias  = (const float*)d_in[4];
  float* out = (float*)d_out;

  size_t need = 16 + (size_t)OUT_SZ * KPAD * 2;
  if (ws_size < need) return;

  unsigned* mm = (unsigned*)d_ws;
  unsigned short* w = (unsigned short*)((char*)d_ws + 16);

  wprep_init<<<(OUT_SZ * IN_SZ) / 256, 256, 0, stream>>>(coef, scale, w, mm);
  minmax_kernel<<<1024, 256, 0, stream>>>(x, mm, (B_SZ * IN_SZ) / 4);
  dim3 g(B_SZ / 128, OUT_SZ / 128);
  kan_gemm<<<g, 256, 0, stream>>>(x, w, bias, mm, out);
}

// Round 3
// 147.698 us; speedup vs baseline: 1.2055x; 1.1112x over previous
//
#include <hip/hip_runtime.h>
#include <stdint.h>

// KAN layer as bf16 MFMA GEMM: out = phi @ W^T + bias
//   phi[b, i*8+g] = normalized cubic-bump basis (g<5; 3 zero-pad cols)
//   W  [o, i*8+g] = coef[o,i,g]*scale[o,i] (bf16, in d_ws)
// M=32768, N=256, K=2048 (padded from 1280).
// R3: 64x128 tile -> 1024 blocks = 4 blocks/CU (50% occ cap, was 18%);
//     basis: max(1-d^3,0) identity + fma/abs-modifier form (~40 VALU/octet);
//     minmax: two-stage partials, no contended atomics (was ~2048 serialized
//     far-atomics on 2 addresses).

#define B_SZ   32768
#define IN_SZ  256
#define OUT_SZ 256
#define KPAD   2048
#define EPSF   1e-8f

#define A_STRIDE 40                 // ushorts; 80 B rows
#define A_ROWS   64
#define AB_BUF   (A_ROWS * A_STRIDE)  // 2560 ushorts / buffer
#define BB_BUF   (128 * 32)           // 4096 ushorts / buffer

typedef __bf16 bf16x8 __attribute__((ext_vector_type(8)));
typedef unsigned short ushort8 __attribute__((ext_vector_type(8)));
typedef float floatx16 __attribute__((ext_vector_type(16)));

__device__ __forceinline__ unsigned short f2bf(float f) {
  unsigned u = __float_as_uint(f);
  u += 0x7FFFu + ((u >> 16) & 1u);
  return (unsigned short)(u >> 16);
}

// W[o][i*8+g] = coef[o][i][g]*scale[o][i], g<5; zeros pad. bf16 bits.
__global__ void __launch_bounds__(256) wprep_kernel(const float* __restrict__ coef,
                                                    const float* __restrict__ scale,
                                                    unsigned short* __restrict__ w) {
  int idx = blockIdx.x * 256 + threadIdx.x;   // o*256 + i
  float s = scale[idx];
  const float* c = coef + idx * 5;
  ushort8 v;
  v[0] = f2bf(c[0] * s); v[1] = f2bf(c[1] * s); v[2] = f2bf(c[2] * s);
  v[3] = f2bf(c[3] * s); v[4] = f2bf(c[4] * s);
  v[5] = 0; v[6] = 0; v[7] = 0;
  *(ushort8*)(w + idx * 8) = v;
}

// minmax stage 1: per-block partial min/max -> part[2*blk], part[2*blk+1]
__global__ void __launch_bounds__(256) mm1_kernel(const float* __restrict__ x,
                                                  float* __restrict__ part, int n4) {
  const float4* x4 = (const float4*)x;
  float lmin = 1e30f, lmax = -1e30f;
  for (int i = blockIdx.x * 256 + threadIdx.x; i < n4; i += gridDim.x * 256) {
    float4 v = x4[i];
    lmin = fminf(lmin, fminf(fminf(v.x, v.y), fminf(v.z, v.w)));
    lmax = fmaxf(lmax, fmaxf(fmaxf(v.x, v.y), fmaxf(v.z, v.w)));
  }
  #pragma unroll
  for (int off = 32; off >= 1; off >>= 1) {
    lmin = fminf(lmin, __shfl_down(lmin, off, 64));
    lmax = fmaxf(lmax, __shfl_down(lmax, off, 64));
  }
  __shared__ float smn[4], smx[4];
  int t = threadIdx.x;
  if ((t & 63) == 0) { smn[t >> 6] = lmin; smx[t >> 6] = lmax; }
  __syncthreads();
  if (t == 0) {
    float mn = fminf(fminf(smn[0], smn[1]), fminf(smn[2], smn[3]));
    float mx = fmaxf(fmaxf(smx[0], smx[1]), fmaxf(smx[2], smx[3]));
    part[2 * blockIdx.x] = mn;
    part[2 * blockIdx.x + 1] = mx;
  }
}

// minmax stage 2: reduce 256 partials; emit sc = 2/(mx-mn+eps), off = -mn*sc-1
__global__ void __launch_bounds__(256) mm2_kernel(const float* __restrict__ part,
                                                  float* __restrict__ scv) {
  int t = threadIdx.x;
  float mn = part[2 * t], mx = part[2 * t + 1];
  #pragma unroll
  for (int off = 32; off >= 1; off >>= 1) {
    mn = fminf(mn, __shfl_down(mn, off, 64));
    mx = fmaxf(mx, __shfl_down(mx, off, 64));
  }
  __shared__ float smn[4], smx[4];
  if ((t & 63) == 0) { smn[t >> 6] = mn; smx[t >> 6] = mx; }
  __syncthreads();
  if (t == 0) {
    mn = fminf(fminf(smn[0], smn[1]), fminf(smn[2], smn[3]));
    mx = fmaxf(fmaxf(smx[0], smx[1]), fmaxf(smx[2], smx[3]));
    float sc = 2.0f / (mx - mn + EPSF);
    scv[0] = sc;
    scv[1] = -mn * sc - 1.0f;
  }
}

__global__ void __launch_bounds__(256, 4) kan_gemm(
    const float* __restrict__ x,            // [32768][256]
    const unsigned short* __restrict__ w,   // [256][2048] bf16 bits
    const float* __restrict__ bias,         // [256]
    const float* __restrict__ scv,          // {sc, off}
    float* __restrict__ out)                // [32768][256]
{
  __shared__ __align__(16) unsigned short Ab[2 * AB_BUF]; // 10 KB
  __shared__ __align__(16) unsigned short Bb[2 * BB_BUF]; // 16 KB

  const int t = threadIdx.x;
  const int lane = t & 63;
  const int wv = t >> 6;
  const int wm = wv & 1, wn = wv >> 1;       // 2x2 waves: 32-row x 64-col tiles
  const int l31 = lane & 31, lh = lane >> 5;
  const int bRow = blockIdx.x * 64;
  const int bCol = blockIdx.y * 128;

  const float scA = scv[0];
  const float scB = scv[1];

  // basis mapping: thread -> (row = t>>2, i-slot = t&3); 1 octet/thread/iter
  const int arow = t >> 2;
  const int slot = t & 3;
  const float* xrow = x + (size_t)(bRow + arow) * IN_SZ;
  unsigned short* awp = Ab + arow * A_STRIDE + slot * 8;

  // B stage: 512 x 16B segs, xor-swizzled slot s=(c4+(o>>1))&3; LDS lane-linear
  auto stageB = [&](int kt, int buf) {
    #pragma unroll
    for (int r = 0; r < 2; ++r) {
      int S = r * 256 + t;
      int o = S >> 2, s = S & 3;
      int c4 = (s - (o >> 1)) & 3;
      const unsigned short* g = w + (size_t)(bCol + o) * KPAD + kt * 32 + c4 * 8;
      __builtin_amdgcn_global_load_lds(
          (const __attribute__((address_space(1))) unsigned int*)g,
          (__attribute__((address_space(3))) unsigned int*)(Bb + buf * BB_BUF + S * 8),
          16, 0, 0);
    }
  };

  // one basis octet: 5 bumps, normalize, pack bf16. where(d<1,1-d^3,0)==max(1-d^3,0)
  auto basis = [&](float xval, int buf) {
    float xn = fmaf(xval, scA, scB);
    float d0 = xn + 1.0f, d1 = xn + 0.5f, d2 = xn, d3 = xn - 0.5f, d4 = xn - 1.0f;
    float b0 = fmaxf(fmaf(d0 * d0, -fabsf(d0), 1.0f), 0.0f);
    float b1 = fmaxf(fmaf(d1 * d1, -fabsf(d1), 1.0f), 0.0f);
    float b2 = fmaxf(fmaf(d2 * d2, -fabsf(d2), 1.0f), 0.0f);
    float b3 = fmaxf(fmaf(d3 * d3, -fabsf(d3), 1.0f), 0.0f);
    float b4 = fmaxf(fmaf(d4 * d4, -fabsf(d4), 1.0f), 0.0f);
    float sum = ((b0 + b1) + (b2 + b3)) + (b4 + EPSF);
    float inv = __builtin_amdgcn_rcpf(sum);
    bf16x8 av = {};
    av[0] = (__bf16)(b0 * inv); av[1] = (__bf16)(b1 * inv);
    av[2] = (__bf16)(b2 * inv); av[3] = (__bf16)(b3 * inv);
    av[4] = (__bf16)(b4 * inv);
    *(bf16x8*)(awp + buf * AB_BUF) = av;
  };

  float xvc[8], xvn[8];
  auto loadx = [&](float* xv, int ic) {
    #pragma unroll
    for (int kk = 0; kk < 8; ++kk)
      xv[kk] = xrow[ic * 32 + kk * 4 + slot];
  };

  floatx16 acc[2] = {};

  // prologue: stage iter 0 into buffer 0
  stageB(0, 0);
  loadx(xvc, 0);
  basis(xvc[0], 0);

  for (int ic = 0; ic < 8; ++ic) {
    #pragma unroll
    for (int kk = 0; kk < 8; ++kk) {
      const int kt = ic * 8 + kk;
      const int cur = kk & 1;        // compile-time buffer select
      const int nxt = cur ^ 1;

      __syncthreads();               // drains stage(kt) vmem + basis ds_writes

      if (kt < 63) {                 // prefetch kt+1, overlapped with compute
        stageB(kt + 1, nxt);
        if (kk == 1 && ic < 7) loadx(xvn, ic + 1);
        float xp = (kk == 7) ? xvn[0] : xvc[kk + 1];
        basis(xp, nxt);
      }

      // compute iter kt: 2 k-steps of 32x32x16, wave tile 32x64
      #pragma unroll
      for (int ks = 0; ks < 2; ++ks) {
        bf16x8 af = *(const bf16x8*)(Ab + cur * AB_BUF +
                      (wm * 32 + l31) * A_STRIDE + (ks * 2 + lh) * 8);
        #pragma unroll
        for (int ni = 0; ni < 2; ++ni) {
          int o = wn * 64 + ni * 32 + l31;
          int s = ((ks * 2 + lh) + (o >> 1)) & 3;    // xor-swizzle slot
          bf16x8 bfr = *(const bf16x8*)(Bb + cur * BB_BUF + o * 32 + s * 8);
          acc[ni] = __builtin_amdgcn_mfma_f32_32x32x16_bf16(af, bfr, acc[ni], 0, 0, 0);
        }
      }
    }
    if (ic < 7) {
      #pragma unroll
      for (int kk = 0; kk < 8; ++kk) xvc[kk] = xvn[kk];
    }
  }

  // epilogue: C/D layout col=lane&31, row=(reg&3)+8*(reg>>2)+4*(lane>>5)
  #pragma unroll
  for (int ni = 0; ni < 2; ++ni) {
    int o = bCol + wn * 64 + ni * 32 + l31;
    float bs = bias[o];
    int rb = bRow + wm * 32 + 4 * lh;
    #pragma unroll
    for (int reg = 0; reg < 16; ++reg) {
      int row = rb + (reg & 3) + 8 * (reg >> 2);
      out[(size_t)row * OUT_SZ + o] = acc[ni][reg] + bs;
    }
  }
}

extern "C" void kernel_launch(void* const* d_in, const int* in_sizes, int n_in,
                              void* d_out, int out_size, void* d_ws, size_t ws_size,
                              hipStream_t stream) {
  const float* x     = (const float*)d_in[0];
  // d_in[1] = grid: linspace(-1,1,5), hardcoded
  const float* coef  = (const float*)d_in[2];
  const float* scale = (const float*)d_in[3];
  const float* bias  = (const float*)d_in[4];
  float* out = (float*)d_out;

  // ws: [0..2048) stage-1 partials (256 float2), [2048..2056) {sc,off},
  //     [4096..) W bf16 [256][2048] = 1 MB
  size_t need = 4096 + (size_t)OUT_SZ * KPAD * 2;
  if (ws_size < need) return;

  float* part = (float*)d_ws;
  float* scv  = (float*)((char*)d_ws + 2048);
  unsigned short* w = (unsigned short*)((char*)d_ws + 4096);

  wprep_kernel<<<(OUT_SZ * IN_SZ) / 256, 256, 0, stream>>>(coef, scale, w);
  mm1_kernel<<<256, 256, 0, stream>>>(x, part, (B_SZ * IN_SZ) / 4);
  mm2_kernel<<<1, 256, 0, stream>>>(part, scv);
  dim3 g(B_SZ / 64, OUT_SZ / 128);
  kan_gemm<<<g, 256, 0, stream>>>(x, w, bias, scv, out);
}

// Round 4
// 142.432 us; speedup vs baseline: 1.2501x; 1.0370x over previous
//
#include <hip/hip_runtime.h>
#include <stdint.h>

// KAN layer as bf16 MFMA GEMM: out = phi @ W^T + bias
//   phi[b, i*8+g] = normalized cubic-bump basis (g<5; 3 zero-pad cols)
// M=32768, N=256, K=2048 (64 kt-iters of BK=32).
// R4: B (W) bypasses LDS entirely — stored in MFMA-fragment order in d_ws,
//     loaded global->VGPR as coalesced dwordx4, register-prefetched 2 iters
//     ahead (W = 1 MB, L2-resident). LDS holds only the basis A tile.
//     R3 was LDS-BW-bound (~46 us of LDS traffic); this cuts LDS bytes 3x.
//     Also: prep fused to 1 kernel, minmax finale folded into gemm prologue
//     (2 launches total, was 4).

#define B_SZ   32768
#define IN_SZ  256
#define OUT_SZ 256
#define EPSF   1e-8f

#define A_STRIDE 40                   // ushorts; 80 B rows
#define AB_BUF   (128 * A_STRIDE)     // 5120 ushorts per buffer

typedef __bf16 bf16x8 __attribute__((ext_vector_type(8)));
typedef unsigned short ushort8 __attribute__((ext_vector_type(8)));
typedef float floatx16 __attribute__((ext_vector_type(16)));

__device__ __forceinline__ unsigned short f2bf(float f) {
  unsigned u = __float_as_uint(f);
  u += 0x7FFFu + ((u >> 16) & 1u);
  return (unsigned short)(u >> 16);
}

// Wf fragment-order chunk index for (o, i): 16B chunk = 8 bf16 g-slots.
//   chunk = (((o>>5)*64 + (i>>2))*2 + ((i>>1)&1))*64 + (i&1)*32 + (o&31)
// In the gemm, chunk == wave-uniform base + lane  -> coalesced dwordx4.

// Fused prep: blocks [0,256) pack W into fragment order; [256,512) do
// per-block min/max partials of x.
__global__ void __launch_bounds__(256) prep_kernel(const float* __restrict__ coef,
                                                   const float* __restrict__ scale,
                                                   const float* __restrict__ x,
                                                   unsigned short* __restrict__ wf,
                                                   float* __restrict__ part, int n4) {
  const int t = threadIdx.x;
  if (blockIdx.x < 256) {
    int idx = blockIdx.x * 256 + t;        // o*256 + i
    int o = idx >> 8, i = idx & 255;
    float s = scale[idx];
    const float* c = coef + (size_t)idx * 5;
    ushort8 v;
    v[0] = f2bf(c[0] * s); v[1] = f2bf(c[1] * s); v[2] = f2bf(c[2] * s);
    v[3] = f2bf(c[3] * s); v[4] = f2bf(c[4] * s);
    v[5] = 0; v[6] = 0; v[7] = 0;
    int chunk = (((o >> 5) * 64 + (i >> 2)) * 2 + ((i >> 1) & 1)) * 64
                + (i & 1) * 32 + (o & 31);
    *(ushort8*)(wf + (size_t)chunk * 8) = v;
  } else {
    int mb = blockIdx.x - 256;
    const float4* x4 = (const float4*)x;
    float lmin = 1e30f, lmax = -1e30f;
    for (int i = mb * 256 + t; i < n4; i += 256 * 256) {
      float4 v = x4[i];
      lmin = fminf(lmin, fminf(fminf(v.x, v.y), fminf(v.z, v.w)));
      lmax = fmaxf(lmax, fmaxf(fmaxf(v.x, v.y), fmaxf(v.z, v.w)));
    }
    #pragma unroll
    for (int off = 32; off >= 1; off >>= 1) {
      lmin = fminf(lmin, __shfl_down(lmin, off, 64));
      lmax = fmaxf(lmax, __shfl_down(lmax, off, 64));
    }
    __shared__ float smn[4], smx[4];
    if ((t & 63) == 0) { smn[t >> 6] = lmin; smx[t >> 6] = lmax; }
    __syncthreads();
    if (t == 0) {
      float mn = fminf(fminf(smn[0], smn[1]), fminf(smn[2], smn[3]));
      float mx = fmaxf(fmaxf(smx[0], smx[1]), fmaxf(smx[2], smx[3]));
      part[2 * mb] = mn;
      part[2 * mb + 1] = mx;
    }
  }
}

__global__ void __launch_bounds__(256, 2) kan_gemm(
    const float* __restrict__ x,            // [32768][256]
    const unsigned short* __restrict__ wf,  // fragment-ordered W, 1 MB
    const float* __restrict__ bias,         // [256]
    const float* __restrict__ part,         // 256 {min,max} partials
    float* __restrict__ out)                // [32768][256]
{
  __shared__ __align__(16) unsigned short Ab[2 * AB_BUF]; // 20 KB
  __shared__ float2 red[4];

  const int t = threadIdx.x;
  const int lane = t & 63;
  const int wv = t >> 6;
  const int wm = wv & 1, wn = wv >> 1;       // 2x2 waves, 64x64 wave tiles
  const int l31 = lane & 31, lh = lane >> 5;
  const int bRow = blockIdx.x * 128;
  const int bCol = blockIdx.y * 128;

  // ---- B fragment addressing (global->VGPR, coalesced) ----
  // addr(ni, ks, kt) ushorts = ((((ogB+ni)*64 + kt)*2 + ks)*64 + lane)*8
  const int ogB = blockIdx.y * 4 + wn * 2;
  const unsigned short* wfl = wf + (size_t)lane * 8;
  auto loadB = [&](int kt, bf16x8 (*dst)[2]) {
    #pragma unroll
    for (int ks = 0; ks < 2; ++ks)
      #pragma unroll
      for (int ni = 0; ni < 2; ++ni)
        dst[ks][ni] = *(const bf16x8*)(wfl +
            (size_t)((((ogB + ni) * 64 + kt) * 2 + ks)) * 512);
  };

  // ---- basis mapping: thread -> (row=t>>1, slots (t&1)*2+{0,1}) ----
  const int arow = t >> 1;
  const int sl2 = (t & 1) * 2;
  const float* xrow = x + (size_t)(bRow + arow) * IN_SZ;
  unsigned short* awp = Ab + arow * A_STRIDE + sl2 * 8;

  // ---- prologue: B/x loads in flight while reducing minmax partials ----
  bf16x8 bReg[2][2][2];                      // [parity][ks][ni]
  loadB(0, bReg[0]);
  loadB(1, bReg[1]);
  float2 xv[2];
  xv[0] = *(const float2*)(xrow + 0 * 4 + sl2);
  xv[1] = *(const float2*)(xrow + 1 * 4 + sl2);

  float2 p = ((const float2*)part)[t];
  float mn = p.x, mx = p.y;
  #pragma unroll
  for (int off = 32; off >= 1; off >>= 1) {
    mn = fminf(mn, __shfl_down(mn, off, 64));
    mx = fmaxf(mx, __shfl_down(mx, off, 64));
  }
  if ((lane) == 0) red[wv] = make_float2(mn, mx);
  __syncthreads();
  mn = fminf(fminf(red[0].x, red[1].x), fminf(red[2].x, red[3].x));
  mx = fmaxf(fmaxf(red[0].y, red[1].y), fmaxf(red[2].y, red[3].y));
  const float scA = 2.0f / (mx - mn + EPSF);
  const float scB = -mn * scA - 1.0f;

  // one basis octet: where(d<1,1-d^3,0) == max(1-d^3,0); normalize; pack bf16
  auto basis = [&](float2 xp, int buf) {
    #pragma unroll
    for (int j = 0; j < 2; ++j) {
      float xn = fmaf(j ? xp.y : xp.x, scA, scB);
      float d0 = xn + 1.0f, d1 = xn + 0.5f, d3 = xn - 0.5f, d4 = xn - 1.0f;
      float b0 = fmaxf(fmaf(d0 * d0, -fabsf(d0), 1.0f), 0.0f);
      float b1 = fmaxf(fmaf(d1 * d1, -fabsf(d1), 1.0f), 0.0f);
      float b2 = fmaxf(fmaf(xn * xn, -fabsf(xn), 1.0f), 0.0f);
      float b3 = fmaxf(fmaf(d3 * d3, -fabsf(d3), 1.0f), 0.0f);
      float b4 = fmaxf(fmaf(d4 * d4, -fabsf(d4), 1.0f), 0.0f);
      float sum = ((b0 + b1) + (b2 + b3)) + (b4 + EPSF);
      float inv = __builtin_amdgcn_rcpf(sum);
      bf16x8 av = {};
      av[0] = (__bf16)(b0 * inv); av[1] = (__bf16)(b1 * inv);
      av[2] = (__bf16)(b2 * inv); av[3] = (__bf16)(b3 * inv);
      av[4] = (__bf16)(b4 * inv);
      *(bf16x8*)(awp + buf * AB_BUF + j * 8) = av;
    }
  };

  basis(xv[0], 0);

  floatx16 acc[2][2] = {};

  for (int base = 0; base < 64; base += 2) {
    #pragma unroll
    for (int u = 0; u < 2; ++u) {
      const int kt = base + u;
      const int cur = u, nxt = u ^ 1;

      __syncthreads();   // basis(kt) now visible; prefetches are >=1 iter old

      // A fragments for iter kt
      bf16x8 af[2][2];   // [ks][mi]
      #pragma unroll
      for (int ks = 0; ks < 2; ++ks)
        #pragma unroll
        for (int mi = 0; mi < 2; ++mi)
          af[ks][mi] = *(const bf16x8*)(Ab + cur * AB_BUF +
              (wm * 64 + mi * 32 + l31) * A_STRIDE + (ks * 2 + lh) * 8);

      // next iter's basis (overlaps with this iter's MFMA)
      if (kt < 63) basis(xv[nxt], nxt);

      #pragma unroll
      for (int ks = 0; ks < 2; ++ks)
        #pragma unroll
        for (int mi = 0; mi < 2; ++mi)
          #pragma unroll
          for (int ni = 0; ni < 2; ++ni)
            acc[mi][ni] = __builtin_amdgcn_mfma_f32_32x32x16_bf16(
                af[ks][mi], bReg[cur][ks][ni], acc[mi][ni], 0, 0, 0);

      // refill parity `cur` with iter kt+2 (consumed above; ~1.5-iter window)
      if (kt < 62) {
        loadB(kt + 2, bReg[cur]);
        xv[cur] = *(const float2*)(xrow + (kt + 2) * 4 + sl2);
      }
    }
  }

  // epilogue: C/D col=lane&31, row=(reg&3)+8*(reg>>2)+4*(lane>>5) [m74/m101]
  #pragma unroll
  for (int ni = 0; ni < 2; ++ni) {
    int o = bCol + wn * 64 + ni * 32 + l31;
    float bs = bias[o];
    #pragma unroll
    for (int mi = 0; mi < 2; ++mi) {
      int rb = bRow + wm * 64 + mi * 32 + 4 * lh;
      #pragma unroll
      for (int reg = 0; reg < 16; ++reg) {
        int row = rb + (reg & 3) + 8 * (reg >> 2);
        out[(size_t)row * OUT_SZ + o] = acc[mi][ni][reg] + bs;
      }
    }
  }
}

extern "C" void kernel_launch(void* const* d_in, const int* in_sizes, int n_in,
                              void* d_out, int out_size, void* d_ws, size_t ws_size,
                              hipStream_t stream) {
  const float* x     = (const float*)d_in[0];
  // d_in[1] = grid: linspace(-1,1,5), hardcoded
  const float* coef  = (const float*)d_in[2];
  const float* scale = (const float*)d_in[3];
  const float* bias  = (const float*)d_in[4];
  float* out = (float*)d_out;

  // ws: [0..2048) minmax partials (256 float2), [4096..) Wf (1 MB)
  size_t need = 4096 + (size_t)OUT_SZ * IN_SZ * 8 * 2;
  if (ws_size < need) return;

  float* part = (float*)d_ws;
  unsigned short* wf = (unsigned short*)((char*)d_ws + 4096);

  prep_kernel<<<512, 256, 0, stream>>>(coef, scale, x, wf, part,
                                       (B_SZ * IN_SZ) / 4);
  dim3 g(B_SZ / 128, OUT_SZ / 128);
  kan_gemm<<<g, 256, 0, stream>>>(x, wf, bias, part, out);
}